// Round 3
// baseline (244.869 us; speedup 1.0000x reference)
//
#include <hip/hip_runtime.h>

#define NROWS 4096
#define TLEN  2048
#define BLOCK 512
#define PER_THREAD 4    // TLEN / BLOCK  -> exactly one float4 per thread per array
#define NWAVES (BLOCK/64)
#define LAMBDA 0.95f
#define RBLOCK 256

typedef float v4f __attribute__((ext_vector_type(4)));
typedef int   v4i __attribute__((ext_vector_type(4)));

__global__ __launch_bounds__(BLOCK, 4) void retrace_loss_kernel(
    const float* __restrict__ current_qf,
    const float* __restrict__ target_qf_tp1,
    const float* __restrict__ target_q_tp1,
    const float* __restrict__ rewards,
    const float* __restrict__ pcont,
    const float* __restrict__ logpacs,
    const float* __restrict__ old_logpacs,
    const float* __restrict__ entropy_p,
    const int*   __restrict__ timeout,
    float* __restrict__ partials)            // [NROWS] block partial sums
{
    const int row  = blockIdx.x;
    const int tid  = threadIdx.x;
    const int lane = tid & 63;
    const int wave = tid >> 6;
    // R6 (3rd submission; two broker timeouts, no data yet): CACHE
    // PARTITIONING. All-nt (R5) left the 268 MB input set thrashing the
    // 256 MB L3 at ~50% residency (FETCH = 134 MB/dispatch, blended
    // 5.75 TB/s while HBM sat at 36% peak). Split the set: 6 arrays
    // (201.3 MB, fits L3 with 55 MB headroom) use TEMPORAL loads so the L3
    // pins them across iterations; 2 arrays (logpacs/old_logpacs, 67 MB)
    // stay nt so the streamed lines never evict the resident set.
    const int vidx = (row * TLEN) / 4 + tid;

    v4f vq  = ((const v4f*)current_qf   )[vidx];                           // temporal (L3-resident set)
    v4f vtq = ((const v4f*)target_qf_tp1)[vidx];                           // temporal
    v4f vtv = ((const v4f*)target_q_tp1 )[vidx];                           // temporal
    v4f vrw = ((const v4f*)rewards      )[vidx];                           // temporal
    v4f vpc = ((const v4f*)pcont        )[vidx];                           // temporal
    v4f vlp = __builtin_nontemporal_load(((const v4f*)logpacs    ) + vidx); // streamed
    v4f vol = __builtin_nontemporal_load(((const v4f*)old_logpacs) + vidx); // streamed
    v4i vto = ((const v4i*)timeout      )[vidx];                           // temporal
    const float ent = entropy_p[0];

    float cq[PER_THREAD]  = {vq.x, vq.y, vq.z, vq.w};
    float tqf[PER_THREAD] = {vtq.x,vtq.y,vtq.z,vtq.w};
    float tv[PER_THREAD]  = {vtv.x,vtv.y,vtv.z,vtv.w};
    float rw[PER_THREAD]  = {vrw.x,vrw.y,vrw.z,vrw.w};
    float pc[PER_THREAD]  = {vpc.x,vpc.y,vpc.z,vpc.w};
    float lp[PER_THREAD]  = {vlp.x,vlp.y,vlp.z,vlp.w};
    float olp[PER_THREAD] = {vol.x,vol.y,vol.z,vol.w};
    int   to[PER_THREAD]  = {vto.x,vto.y,vto.z,vto.w};

    // ---- per-element affine coefficients: q[t] = a[t] + b[t]*q[t+1] ----
    float aco[PER_THREAD], bco[PER_THREAD];
    #pragma unroll
    for (int j = 0; j < PER_THREAD; ++j) {
        float m  = to[j] ? 0.0f : 1.0f;
        float c  = LAMBDA * __expf(fminf(lp[j] - olp[j], 0.0f));
        float mc = m * c;
        bco[j] = pc[j] * mc;
        aco[j] = rw[j] + pc[j] * (tv[j] + ent - mc * tqf[j]);
    }
    // terminal: q[T-1] = target_qf_tp1[:, -1]  (b=0 kills any carry)
    if (tid == BLOCK - 1) { aco[PER_THREAD-1] = tqf[PER_THREAD-1]; bco[PER_THREAD-1] = 0.0f; }

    // ---- per-thread chunk composition (right-to-left): q[lo] = A + B*carry ----
    float A = aco[PER_THREAD-1], Bc = bco[PER_THREAD-1];
    #pragma unroll
    for (int j = PER_THREAD - 2; j >= 0; --j) { A = aco[j] + bco[j] * A; Bc = bco[j] * Bc; }

    // ---- wave-level inclusive suffix scan of affine pairs (Hillis-Steele) ----
    float sA = A, sB = Bc;
    #pragma unroll
    for (int off = 1; off < 64; off <<= 1) {
        float nA = __shfl_down(sA, off);
        float nB = __shfl_down(sB, off);
        if (lane + off < 64) { sA = sA + sB * nA; sB = sB * nB; }
    }
    // exclusive suffix within wave: lane i gets inclusive of lane i+1; lane 63 = identity
    float eA = __shfl_down(sA, 1);
    float eB = __shfl_down(sB, 1);
    if (lane == 63) { eA = 0.0f; eB = 1.0f; }

    // ---- wave carries via LDS (NWAVES waves) ----
    __shared__ float wA[NWAVES], wB[NWAVES], psum[NWAVES];
    if (lane == 0) { wA[wave] = sA; wB[wave] = sB; }  // inclusive at lane 0 = whole-wave comp
    __syncthreads();
    float gA = 0.0f, gB = 1.0f;               // compose waves to the right of this wave
    for (int j = wave + 1; j < NWAVES; ++j) { gA = gA + gB * wA[j]; gB = gB * wB[j]; }

    // carry into this thread's chunk (seed irrelevant: composed B through tail is 0)
    float carry = eA + eB * gA;

    // ---- replay chunk sequentially (matches reference fp32 order), MSE accumulate ----
    float q = carry;
    float sum = 0.0f;
    #pragma unroll
    for (int j = PER_THREAD - 1; j >= 0; --j) {
        q = aco[j] + bco[j] * q;              // q_ret[t]
        float d = cq[j] - q;
        sum += d * d;
    }

    // ---- block reduction -> ONE uncontended store per block (no atomics) ----
    #pragma unroll
    for (int off = 32; off > 0; off >>= 1) sum += __shfl_down(sum, off);
    if (lane == 0) psum[wave] = sum;
    __syncthreads();
    if (tid == 0) {
        float s = 0.0f;
        #pragma unroll
        for (int j = 0; j < NWAVES; ++j) s += psum[j];
        __builtin_nontemporal_store(s, partials + row);  // single-use scratch, keep out of L3
    }
}

// reduce 4096 partials -> mean; single block, no atomics
__global__ __launch_bounds__(RBLOCK) void reduce_kernel(
    const float* __restrict__ partials, float* __restrict__ out)
{
    const int tid  = threadIdx.x;
    const int lane = tid & 63;
    const int wave = tid >> 6;
    float sum = 0.0f;
    #pragma unroll
    for (int k = 0; k < NROWS / RBLOCK / 4; ++k) {          // 4 float4 per thread
        float4 v = ((const float4*)partials)[tid + k * RBLOCK];
        sum += v.x + v.y + v.z + v.w;
    }
    #pragma unroll
    for (int off = 32; off > 0; off >>= 1) sum += __shfl_down(sum, off);
    __shared__ float psum[4];
    if (lane == 0) psum[wave] = sum;
    __syncthreads();
    if (tid == 0) {
        float s = psum[0] + psum[1] + psum[2] + psum[3];
        out[0] = s * (1.0f / ((float)NROWS * (float)TLEN));
    }
}

extern "C" void kernel_launch(void* const* d_in, const int* in_sizes, int n_in,
                              void* d_out, int out_size, void* d_ws, size_t ws_size,
                              hipStream_t stream) {
    const float* current_qf     = (const float*)d_in[0];
    const float* target_qf_tp1  = (const float*)d_in[1];
    const float* target_q_tp1   = (const float*)d_in[2];
    const float* rewards        = (const float*)d_in[3];
    const float* pcont          = (const float*)d_in[4];
    const float* logpacs        = (const float*)d_in[5];
    const float* old_logpacs    = (const float*)d_in[6];
    const float* entropy        = (const float*)d_in[7];
    const int*   timeout        = (const int*)d_in[8];
    float* partials = (float*)d_ws;          // 4096 floats = 16 KB scratch
    float* out = (float*)d_out;

    retrace_loss_kernel<<<NROWS, BLOCK, 0, stream>>>(
        current_qf, target_qf_tp1, target_q_tp1, rewards, pcont,
        logpacs, old_logpacs, entropy, timeout, partials);
    reduce_kernel<<<1, RBLOCK, 0, stream>>>(partials, out);
}

// Round 6
// 227.863 us; speedup vs baseline: 1.0746x; 1.0746x over previous
//
#include <hip/hip_runtime.h>

#define NROWS 4096
#define TLEN  2048
#define BLOCK 512
#define PER_THREAD 4    // TLEN / BLOCK  -> exactly one float4 per thread per array
#define NWAVES (BLOCK/64)
#define LAMBDA 0.95f
#define RBLOCK 256

typedef float v4f __attribute__((ext_vector_type(4)));
typedef int   v4i __attribute__((ext_vector_type(4)));

__global__ __launch_bounds__(BLOCK, 4) void retrace_loss_kernel(
    const float* __restrict__ current_qf,
    const float* __restrict__ target_qf_tp1,
    const float* __restrict__ target_q_tp1,
    const float* __restrict__ rewards,
    const float* __restrict__ pcont,
    const float* __restrict__ logpacs,
    const float* __restrict__ old_logpacs,
    const float* __restrict__ entropy_p,
    const int*   __restrict__ timeout,
    float* __restrict__ partials)            // [NROWS] block partial sums
{
    const int row  = blockIdx.x;
    const int tid  = threadIdx.x;
    const int lane = tid & 63;
    const int wave = tid >> 6;
    // R7 (3rd submission; broker timeouts on 1st/2nd): REVERT to R5 (all-nt).
    // R6's cache-partitioning test: FETCH_SIZE bit-identical (131,093.5 KB)
    // under temporal vs nt policy — the nt bit does NOT steer L3 residency
    // on gfx950 — while temporal allocation of zero-reuse streams halved
    // delivery (6.4 -> 3.5 TB/s blended, 47 -> 85 µs/dispatch). All-nt at
    // 47 µs delivers 302 MB/dispatch = 6.4 TB/s blended, at/above the
    // 6.29 TB/s D2D copy ceiling: streaming roofline.
    const int vidx = (row * TLEN) / 4 + tid;

    v4f vq  = __builtin_nontemporal_load(((const v4f*)current_qf   ) + vidx);
    v4f vtq = __builtin_nontemporal_load(((const v4f*)target_qf_tp1) + vidx);
    v4f vtv = __builtin_nontemporal_load(((const v4f*)target_q_tp1 ) + vidx);
    v4f vrw = __builtin_nontemporal_load(((const v4f*)rewards      ) + vidx);
    v4f vpc = __builtin_nontemporal_load(((const v4f*)pcont        ) + vidx);
    v4f vlp = __builtin_nontemporal_load(((const v4f*)logpacs      ) + vidx);
    v4f vol = __builtin_nontemporal_load(((const v4f*)old_logpacs  ) + vidx);
    v4i vto = __builtin_nontemporal_load(((const v4i*)timeout      ) + vidx);
    const float ent = entropy_p[0];

    float cq[PER_THREAD]  = {vq.x, vq.y, vq.z, vq.w};
    float tqf[PER_THREAD] = {vtq.x,vtq.y,vtq.z,vtq.w};
    float tv[PER_THREAD]  = {vtv.x,vtv.y,vtv.z,vtv.w};
    float rw[PER_THREAD]  = {vrw.x,vrw.y,vrw.z,vrw.w};
    float pc[PER_THREAD]  = {vpc.x,vpc.y,vpc.z,vpc.w};
    float lp[PER_THREAD]  = {vlp.x,vlp.y,vlp.z,vlp.w};
    float olp[PER_THREAD] = {vol.x,vol.y,vol.z,vol.w};
    int   to[PER_THREAD]  = {vto.x,vto.y,vto.z,vto.w};

    // ---- per-element affine coefficients: q[t] = a[t] + b[t]*q[t+1] ----
    float aco[PER_THREAD], bco[PER_THREAD];
    #pragma unroll
    for (int j = 0; j < PER_THREAD; ++j) {
        float m  = to[j] ? 0.0f : 1.0f;
        float c  = LAMBDA * __expf(fminf(lp[j] - olp[j], 0.0f));
        float mc = m * c;
        bco[j] = pc[j] * mc;
        aco[j] = rw[j] + pc[j] * (tv[j] + ent - mc * tqf[j]);
    }
    // terminal: q[T-1] = target_qf_tp1[:, -1]  (b=0 kills any carry)
    if (tid == BLOCK - 1) { aco[PER_THREAD-1] = tqf[PER_THREAD-1]; bco[PER_THREAD-1] = 0.0f; }

    // ---- per-thread chunk composition (right-to-left): q[lo] = A + B*carry ----
    float A = aco[PER_THREAD-1], Bc = bco[PER_THREAD-1];
    #pragma unroll
    for (int j = PER_THREAD - 2; j >= 0; --j) { A = aco[j] + bco[j] * A; Bc = bco[j] * Bc; }

    // ---- wave-level inclusive suffix scan of affine pairs (Hillis-Steele) ----
    float sA = A, sB = Bc;
    #pragma unroll
    for (int off = 1; off < 64; off <<= 1) {
        float nA = __shfl_down(sA, off);
        float nB = __shfl_down(sB, off);
        if (lane + off < 64) { sA = sA + sB * nA; sB = sB * nB; }
    }
    // exclusive suffix within wave: lane i gets inclusive of lane i+1; lane 63 = identity
    float eA = __shfl_down(sA, 1);
    float eB = __shfl_down(sB, 1);
    if (lane == 63) { eA = 0.0f; eB = 1.0f; }

    // ---- wave carries via LDS (NWAVES waves) ----
    __shared__ float wA[NWAVES], wB[NWAVES], psum[NWAVES];
    if (lane == 0) { wA[wave] = sA; wB[wave] = sB; }  // inclusive at lane 0 = whole-wave comp
    __syncthreads();
    float gA = 0.0f, gB = 1.0f;               // compose waves to the right of this wave
    for (int j = wave + 1; j < NWAVES; ++j) { gA = gA + gB * wA[j]; gB = gB * wB[j]; }

    // carry into this thread's chunk (seed irrelevant: composed B through tail is 0)
    float carry = eA + eB * gA;

    // ---- replay chunk sequentially (matches reference fp32 order), MSE accumulate ----
    float q = carry;
    float sum = 0.0f;
    #pragma unroll
    for (int j = PER_THREAD - 1; j >= 0; --j) {
        q = aco[j] + bco[j] * q;              // q_ret[t]
        float d = cq[j] - q;
        sum += d * d;
    }

    // ---- block reduction -> ONE uncontended store per block (no atomics) ----
    #pragma unroll
    for (int off = 32; off > 0; off >>= 1) sum += __shfl_down(sum, off);
    if (lane == 0) psum[wave] = sum;
    __syncthreads();
    if (tid == 0) {
        float s = 0.0f;
        #pragma unroll
        for (int j = 0; j < NWAVES; ++j) s += psum[j];
        partials[row] = s;
    }
}

// reduce 4096 partials -> mean; single block, no atomics
__global__ __launch_bounds__(RBLOCK) void reduce_kernel(
    const float* __restrict__ partials, float* __restrict__ out)
{
    const int tid  = threadIdx.x;
    const int lane = tid & 63;
    const int wave = tid >> 6;
    float sum = 0.0f;
    #pragma unroll
    for (int k = 0; k < NROWS / RBLOCK / 4; ++k) {          // 4 float4 per thread
        float4 v = ((const float4*)partials)[tid + k * RBLOCK];
        sum += v.x + v.y + v.z + v.w;
    }
    #pragma unroll
    for (int off = 32; off > 0; off >>= 1) sum += __shfl_down(sum, off);
    __shared__ float psum[4];
    if (lane == 0) psum[wave] = sum;
    __syncthreads();
    if (tid == 0) {
        float s = psum[0] + psum[1] + psum[2] + psum[3];
        out[0] = s * (1.0f / ((float)NROWS * (float)TLEN));
    }
}

extern "C" void kernel_launch(void* const* d_in, const int* in_sizes, int n_in,
                              void* d_out, int out_size, void* d_ws, size_t ws_size,
                              hipStream_t stream) {
    const float* current_qf     = (const float*)d_in[0];
    const float* target_qf_tp1  = (const float*)d_in[1];
    const float* target_q_tp1   = (const float*)d_in[2];
    const float* rewards        = (const float*)d_in[3];
    const float* pcont          = (const float*)d_in[4];
    const float* logpacs        = (const float*)d_in[5];
    const float* old_logpacs    = (const float*)d_in[6];
    const float* entropy        = (const float*)d_in[7];
    const int*   timeout        = (const int*)d_in[8];
    float* partials = (float*)d_ws;          // 4096 floats = 16 KB scratch
    float* out = (float*)d_out;

    retrace_loss_kernel<<<NROWS, BLOCK, 0, stream>>>(
        current_qf, target_qf_tp1, target_q_tp1, rewards, pcont,
        logpacs, old_logpacs, entropy, timeout, partials);
    reduce_kernel<<<1, RBLOCK, 0, stream>>>(partials, out);
}

// Round 7
// 223.860 us; speedup vs baseline: 1.0938x; 1.0179x over previous
//
#include <hip/hip_runtime.h>

#define NROWS 4096
#define TLEN  2048
#define BLOCK 512
#define PER_THREAD 4      // elements per thread per row (TLEN / BLOCK)
#define ROWS_PER_BLOCK 2  // R8: 2 rows/block -> 2x MLP per wave, half the blocks
#define NBLOCKS (NROWS / ROWS_PER_BLOCK)   // 2048
#define NWAVES (BLOCK/64)
#define LAMBDA 0.95f
#define RBLOCK 256

typedef float v4f __attribute__((ext_vector_type(4)));
typedef int   v4i __attribute__((ext_vector_type(4)));

__global__ __launch_bounds__(BLOCK, 4) void retrace_loss_kernel(
    const float* __restrict__ current_qf,
    const float* __restrict__ target_qf_tp1,
    const float* __restrict__ target_q_tp1,
    const float* __restrict__ rewards,
    const float* __restrict__ pcont,
    const float* __restrict__ logpacs,
    const float* __restrict__ old_logpacs,
    const float* __restrict__ entropy_p,
    const int*   __restrict__ timeout,
    float* __restrict__ partials)            // [NBLOCKS] block partial sums
{
    const int tid  = threadIdx.x;
    const int lane = tid & 63;
    const int wave = tid >> 6;
    // R8: two rows per block. R7 confirmed all-nt at 46 us/dispatch =
    // 6.56 TB/s blended (302 MB, FETCH 131 MB), above the 6.29 TB/s COPY
    // ceiling. Remaining question: fabric ceiling vs pipeline bubbles
    // (Occupancy 56%, VALUBusy 17%, 16 block-generations/CU, 8-deep MLP).
    // This doubles per-wave loads in flight (18 upfront) and halves block
    // count; traffic identical. Unchanged dur => roofline confirmed.
    const int base0 = (blockIdx.x * ROWS_PER_BLOCK) * (TLEN/4) + tid;  // float4 idx, row 0
    const int base1 = base0 + (TLEN/4);                                // row 1

    // ---- issue ALL global loads upfront (maximize MLP) ----
    v4f vq0  = __builtin_nontemporal_load(((const v4f*)current_qf   ) + base0);
    v4f vq1  = __builtin_nontemporal_load(((const v4f*)current_qf   ) + base1);
    v4f vtq0 = __builtin_nontemporal_load(((const v4f*)target_qf_tp1) + base0);
    v4f vtq1 = __builtin_nontemporal_load(((const v4f*)target_qf_tp1) + base1);
    v4f vtv0 = __builtin_nontemporal_load(((const v4f*)target_q_tp1 ) + base0);
    v4f vtv1 = __builtin_nontemporal_load(((const v4f*)target_q_tp1 ) + base1);
    v4f vrw0 = __builtin_nontemporal_load(((const v4f*)rewards      ) + base0);
    v4f vrw1 = __builtin_nontemporal_load(((const v4f*)rewards      ) + base1);
    v4f vpc0 = __builtin_nontemporal_load(((const v4f*)pcont        ) + base0);
    v4f vpc1 = __builtin_nontemporal_load(((const v4f*)pcont        ) + base1);
    v4f vlp0 = __builtin_nontemporal_load(((const v4f*)logpacs      ) + base0);
    v4f vlp1 = __builtin_nontemporal_load(((const v4f*)logpacs      ) + base1);
    v4f vol0 = __builtin_nontemporal_load(((const v4f*)old_logpacs  ) + base0);
    v4f vol1 = __builtin_nontemporal_load(((const v4f*)old_logpacs  ) + base1);
    v4i vto0 = __builtin_nontemporal_load(((const v4i*)timeout      ) + base0);
    v4i vto1 = __builtin_nontemporal_load(((const v4i*)timeout      ) + base1);
    const float ent = entropy_p[0];

    float cq[2][PER_THREAD]  = {{vq0.x,vq0.y,vq0.z,vq0.w},  {vq1.x,vq1.y,vq1.z,vq1.w}};
    float tqf[2][PER_THREAD] = {{vtq0.x,vtq0.y,vtq0.z,vtq0.w},{vtq1.x,vtq1.y,vtq1.z,vtq1.w}};
    float tv[2][PER_THREAD]  = {{vtv0.x,vtv0.y,vtv0.z,vtv0.w},{vtv1.x,vtv1.y,vtv1.z,vtv1.w}};
    float rw[2][PER_THREAD]  = {{vrw0.x,vrw0.y,vrw0.z,vrw0.w},{vrw1.x,vrw1.y,vrw1.z,vrw1.w}};
    float pc[2][PER_THREAD]  = {{vpc0.x,vpc0.y,vpc0.z,vpc0.w},{vpc1.x,vpc1.y,vpc1.z,vpc1.w}};
    float lp[2][PER_THREAD]  = {{vlp0.x,vlp0.y,vlp0.z,vlp0.w},{vlp1.x,vlp1.y,vlp1.z,vlp1.w}};
    float olp[2][PER_THREAD] = {{vol0.x,vol0.y,vol0.z,vol0.w},{vol1.x,vol1.y,vol1.z,vol1.w}};
    int   to[2][PER_THREAD]  = {{vto0.x,vto0.y,vto0.z,vto0.w},{vto1.x,vto1.y,vto1.z,vto1.w}};

    // ---- per-element affine coefficients: q[t] = a[t] + b[t]*q[t+1] ----
    float aco[2][PER_THREAD], bco[2][PER_THREAD];
    #pragma unroll
    for (int r = 0; r < 2; ++r) {
        #pragma unroll
        for (int j = 0; j < PER_THREAD; ++j) {
            float m  = to[r][j] ? 0.0f : 1.0f;
            float c  = LAMBDA * __expf(fminf(lp[r][j] - olp[r][j], 0.0f));
            float mc = m * c;
            bco[r][j] = pc[r][j] * mc;
            aco[r][j] = rw[r][j] + pc[r][j] * (tv[r][j] + ent - mc * tqf[r][j]);
        }
    }
    // terminal: q[T-1] = target_qf_tp1[:, -1]  (b=0 kills any carry) — both rows
    if (tid == BLOCK - 1) {
        #pragma unroll
        for (int r = 0; r < 2; ++r) { aco[r][PER_THREAD-1] = tqf[r][PER_THREAD-1]; bco[r][PER_THREAD-1] = 0.0f; }
    }

    // ---- per-thread chunk composition (right-to-left): q[lo] = A + B*carry ----
    float A0 = aco[0][PER_THREAD-1], B0 = bco[0][PER_THREAD-1];
    float A1 = aco[1][PER_THREAD-1], B1 = bco[1][PER_THREAD-1];
    #pragma unroll
    for (int j = PER_THREAD - 2; j >= 0; --j) {
        A0 = aco[0][j] + bco[0][j] * A0;  B0 = bco[0][j] * B0;
        A1 = aco[1][j] + bco[1][j] * A1;  B1 = bco[1][j] * B1;
    }

    // ---- wave-level inclusive suffix scan of affine pairs (both rows interleaved) ----
    float sA0 = A0, sB0 = B0, sA1 = A1, sB1 = B1;
    #pragma unroll
    for (int off = 1; off < 64; off <<= 1) {
        float nA0 = __shfl_down(sA0, off), nB0 = __shfl_down(sB0, off);
        float nA1 = __shfl_down(sA1, off), nB1 = __shfl_down(sB1, off);
        if (lane + off < 64) {
            sA0 = sA0 + sB0 * nA0;  sB0 = sB0 * nB0;
            sA1 = sA1 + sB1 * nA1;  sB1 = sB1 * nB1;
        }
    }
    // exclusive suffix within wave: lane i gets inclusive of lane i+1; lane 63 = identity
    float eA0 = __shfl_down(sA0, 1), eB0 = __shfl_down(sB0, 1);
    float eA1 = __shfl_down(sA1, 1), eB1 = __shfl_down(sB1, 1);
    if (lane == 63) { eA0 = 0.0f; eB0 = 1.0f; eA1 = 0.0f; eB1 = 1.0f; }

    // ---- wave carries via LDS ----
    __shared__ float wA[2][NWAVES], wB[2][NWAVES], psum[NWAVES];
    if (lane == 0) { wA[0][wave] = sA0; wB[0][wave] = sB0; wA[1][wave] = sA1; wB[1][wave] = sB1; }
    __syncthreads();
    float gA0 = 0.0f, gB0 = 1.0f, gA1 = 0.0f, gB1 = 1.0f;   // compose waves to the right
    for (int j = wave + 1; j < NWAVES; ++j) {
        gA0 = gA0 + gB0 * wA[0][j];  gB0 = gB0 * wB[0][j];
        gA1 = gA1 + gB1 * wA[1][j];  gB1 = gB1 * wB[1][j];
    }

    // carry into this thread's chunk (seed irrelevant: composed B through tail is 0)
    float carry0 = eA0 + eB0 * gA0;
    float carry1 = eA1 + eB1 * gA1;

    // ---- replay chunks sequentially (matches reference fp32 order), MSE accumulate ----
    float q0 = carry0, q1 = carry1;
    float sum = 0.0f;
    #pragma unroll
    for (int j = PER_THREAD - 1; j >= 0; --j) {
        q0 = aco[0][j] + bco[0][j] * q0;
        q1 = aco[1][j] + bco[1][j] * q1;
        float d0 = cq[0][j] - q0;
        float d1 = cq[1][j] - q1;
        sum += d0 * d0 + d1 * d1;
    }

    // ---- block reduction -> ONE uncontended store per block (no atomics) ----
    #pragma unroll
    for (int off = 32; off > 0; off >>= 1) sum += __shfl_down(sum, off);
    if (lane == 0) psum[wave] = sum;
    __syncthreads();
    if (tid == 0) {
        float s = 0.0f;
        #pragma unroll
        for (int j = 0; j < NWAVES; ++j) s += psum[j];
        partials[blockIdx.x] = s;
    }
}

// reduce NBLOCKS partials -> mean; single block, no atomics
__global__ __launch_bounds__(RBLOCK) void reduce_kernel(
    const float* __restrict__ partials, float* __restrict__ out)
{
    const int tid  = threadIdx.x;
    const int lane = tid & 63;
    const int wave = tid >> 6;
    float sum = 0.0f;
    #pragma unroll
    for (int k = 0; k < NBLOCKS / RBLOCK / 4; ++k) {        // 2 float4 per thread
        float4 v = ((const float4*)partials)[tid + k * RBLOCK];
        sum += v.x + v.y + v.z + v.w;
    }
    #pragma unroll
    for (int off = 32; off > 0; off >>= 1) sum += __shfl_down(sum, off);
    __shared__ float psum[4];
    if (lane == 0) psum[wave] = sum;
    __syncthreads();
    if (tid == 0) {
        float s = psum[0] + psum[1] + psum[2] + psum[3];
        out[0] = s * (1.0f / ((float)NROWS * (float)TLEN));
    }
}

extern "C" void kernel_launch(void* const* d_in, const int* in_sizes, int n_in,
                              void* d_out, int out_size, void* d_ws, size_t ws_size,
                              hipStream_t stream) {
    const float* current_qf     = (const float*)d_in[0];
    const float* target_qf_tp1  = (const float*)d_in[1];
    const float* target_q_tp1   = (const float*)d_in[2];
    const float* rewards        = (const float*)d_in[3];
    const float* pcont          = (const float*)d_in[4];
    const float* logpacs        = (const float*)d_in[5];
    const float* old_logpacs    = (const float*)d_in[6];
    const float* entropy        = (const float*)d_in[7];
    const int*   timeout        = (const int*)d_in[8];
    float* partials = (float*)d_ws;          // 2048 floats = 8 KB scratch
    float* out = (float*)d_out;

    retrace_loss_kernel<<<NBLOCKS, BLOCK, 0, stream>>>(
        current_qf, target_qf_tp1, target_q_tp1, rewards, pcont,
        logpacs, old_logpacs, entropy, timeout, partials);
    reduce_kernel<<<1, RBLOCK, 0, stream>>>(partials, out);
}